// Round 11
// baseline (2495.214 us; speedup 1.0000x reference)
//
#include <hip/hip_runtime.h>
#include <stdint.h>

typedef float f4 __attribute__((ext_vector_type(4)));

__device__ __forceinline__ double dot4d(f4 a, f4 b) {
    return (double)a.x * (double)b.x + (double)a.y * (double)b.y
         + (double)a.z * (double)b.z + (double)a.w * (double)b.w;
}

// ---------------------------------------------------------------------------
// DIAGNOSTIC ROUND. Each phase repeated so its dispatch exceeds the ~507 µs
// harness fills and surfaces in rocprof top-5 with counters. `zero` (runtime
// arg, always 0) is folded into addresses so the compiler cannot CSE/DCE the
// repeats. Final memory state identical to the passing R9 split -> absmax 0.
// ---------------------------------------------------------------------------

// K1: score, repeated REPS times (identical global writes each rep).
template <int T, int D, int REPS>
__global__ __launch_bounds__(256)
void score_k_rep(const float* __restrict__ x,
                 const float* __restrict__ pre_w,
                 const float* __restrict__ pre_b,
                 double* __restrict__ s,
                 int zero) {
    constexpr int N4 = D / 4;            // 352
    __shared__ f4 w_sh[N4];

    const int tid  = threadIdx.x;
    const int sub  = tid & 15;
    const int gid  = tid >> 4;           // 0..15
    const int base = blockIdx.x * 64;

    for (int i = tid; i < N4; i += 256) w_sh[i] = ((const f4*)pre_w)[i];
    __syncthreads();

    const double pb = (double)pre_b[0];
    for (int rep = 0; rep < REPS; ++rep) {
        const float* xb = x + (size_t)zero * rep;   // runtime-opaque 0 offset
        #pragma unroll
        for (int m = 0; m < 4; ++m) {
            const int r = base + gid + 16 * m;
            const f4* xr = (const f4*)(xb + (size_t)r * D);
            double a0 = 0, a1 = 0, a2 = 0, a3 = 0;
            #pragma unroll 2
            for (int j = 0; j < 16; j += 4) {
                f4 v0 = xr[sub + 16 * (j + 0)];
                f4 v1 = xr[sub + 16 * (j + 1)];
                f4 v2 = xr[sub + 16 * (j + 2)];
                f4 v3 = xr[sub + 16 * (j + 3)];
                a0 += dot4d(v0, w_sh[sub + 16 * (j + 0)]);
                a1 += dot4d(v1, w_sh[sub + 16 * (j + 1)]);
                a2 += dot4d(v2, w_sh[sub + 16 * (j + 2)]);
                a3 += dot4d(v3, w_sh[sub + 16 * (j + 3)]);
            }
            {
                f4 v0 = xr[sub + 16 * 16];
                f4 v1 = xr[sub + 16 * 17];
                f4 v2 = xr[sub + 16 * 18];
                f4 v3 = xr[sub + 16 * 19];
                f4 v4 = xr[sub + 16 * 20];
                f4 v5 = xr[sub + 16 * 21];
                a0 += dot4d(v0, w_sh[sub + 16 * 16]);
                a1 += dot4d(v1, w_sh[sub + 16 * 17]);
                a2 += dot4d(v2, w_sh[sub + 16 * 18]);
                a3 += dot4d(v3, w_sh[sub + 16 * 19]);
                a0 += dot4d(v4, w_sh[sub + 16 * 20]);
                a1 += dot4d(v5, w_sh[sub + 16 * 21]);
            }
            double a = (a0 + a1) + (a2 + a3);
            a += __shfl_down(a, 8, 16);
            a += __shfl_down(a, 4, 16);
            a += __shfl_down(a, 2, 16);
            a += __shfl_down(a, 1, 16);
            if (sub == 0) s[r] = a + pb;    // same value every rep
        }
    }
}

// K2: select, repeated REPS times (LDS re-initialized per rep; idx_out
// rewritten with identical values each rep).
template <int T, int K, int REPS>
__global__ __launch_bounds__(T)
void select_k_rep(const double* __restrict__ s,
                  const float* __restrict__ W,
                  const float* __restrict__ bias,
                  int* __restrict__ idx_out,
                  int zero) {
    constexpr int NW = (T + 31) / 32;
    __shared__ double   s_sh[T];
    __shared__ double   lg[T];
    __shared__ unsigned flags[NW];

    const int f   = blockIdx.x;
    const int tid = threadIdx.x;

    for (int rep = 0; rep < REPS; ++rep) {
        const double* sp = s + (size_t)zero * rep;
        const float*  Wp = W + (size_t)zero * rep;
        __syncthreads();                      // protect LDS reuse across reps
        s_sh[tid] = sp[(size_t)f * T + tid];
        if (tid < NW) flags[tid] = 0u;
        __syncthreads();

        {
            const float* Wc = Wp + tid;
            double acc[16];
            #pragma unroll
            for (int u = 0; u < 16; ++u) acc[u] = 0.0;
            for (int tp = 0; tp < T; tp += 16) {
                #pragma unroll
                for (int u = 0; u < 16; ++u)
                    acc[u] += s_sh[tp + u] * (double)Wc[(size_t)(tp + u) * T];
            }
            double r0 = (acc[0] + acc[1]) + (acc[2] + acc[3]);
            double r1 = (acc[4] + acc[5]) + (acc[6] + acc[7]);
            double r2 = (acc[8] + acc[9]) + (acc[10] + acc[11]);
            double r3 = (acc[12] + acc[13]) + (acc[14] + acc[15]);
            lg[tid] = ((r0 + r1) + (r2 + r3)) + (double)bias[tid];
        }
        __syncthreads();

        {
            const double v = lg[tid];
            int rank = 0;
            #pragma unroll 8
            for (int tp = 0; tp < T; ++tp) {
                double u = lg[tp];
                rank += (u > v) || (u == v && tp < tid);
            }
            if (rank < K) atomicOr(&flags[tid >> 5], 1u << (tid & 31));
        }
        __syncthreads();

        {
            if ((flags[tid >> 5] >> (tid & 31)) & 1u) {
                int pos = __popc(flags[tid >> 5] & ((1u << (tid & 31)) - 1u));
                for (int u2 = 0; u2 < (tid >> 5); ++u2) pos += __popc(flags[u2]);
                idx_out[(size_t)f * K + pos] = tid;   // same value every rep
            }
        }
    }
}

// K3: gather. REPS-1 read-only passes over ROTATED frames (loads kept live
// via asm sink -> cold reads each rep, pure gather-read rate), final pass is
// the real gather with NT stores.
template <int T, int D, int K, int REPS>
__global__ __launch_bounds__(256)
void gather_k_rep(const float* __restrict__ x,
                  const int* __restrict__ idx,
                  float* __restrict__ out,
                  int F, int zero) {
    constexpr int N4 = D / 4;                // 352
    constexpr int RFULL = N4 / 64;           // 5
    constexpr int RREM  = N4 - RFULL * 64;   // 32

    const int lane = threadIdx.x & 63;
    const int row  = blockIdx.x * 4 + (threadIdx.x >> 6);
    const int f    = row / K;
    const int t    = idx[row];

    float acc = 0.0f;
    #pragma unroll 1
    for (int rep = 0; rep < REPS - 1; ++rep) {
        const int fr = (f + (rep + 1) * 37) % F;       // cold, rotated frame
        const f4* src = (const f4*)(x + ((size_t)fr * T + t) * D)
                        + (size_t)zero * rep;
        f4 v0 = src[lane + 64 * 0];
        f4 v1 = src[lane + 64 * 1];
        f4 v2 = src[lane + 64 * 2];
        f4 v3 = src[lane + 64 * 3];
        f4 v4 = src[lane + 64 * 4];
        acc += v0.x + v0.w + v1.x + v1.w + v2.x + v2.w
             + v3.x + v3.w + v4.x + v4.w;
        if (lane < RREM) {
            f4 v5 = src[lane + 64 * RFULL];
            acc += v5.x + v5.w;
        }
    }
    asm volatile("" :: "v"(acc));            // keep read-only reps alive

    const f4* src = (const f4*)(x + ((size_t)f * T + t) * D);
    f4*       dst = (f4*)(out + (size_t)row * D);
    f4 v0 = src[lane + 64 * 0];
    f4 v1 = src[lane + 64 * 1];
    f4 v2 = src[lane + 64 * 2];
    f4 v3 = src[lane + 64 * 3];
    f4 v4 = src[lane + 64 * 4];
    __builtin_nontemporal_store(v0, &dst[lane + 64 * 0]);
    __builtin_nontemporal_store(v1, &dst[lane + 64 * 1]);
    __builtin_nontemporal_store(v2, &dst[lane + 64 * 2]);
    __builtin_nontemporal_store(v3, &dst[lane + 64 * 3]);
    __builtin_nontemporal_store(v4, &dst[lane + 64 * 4]);
    if (lane < RREM) {
        f4 v5 = src[lane + 64 * RFULL];
        __builtin_nontemporal_store(v5, &dst[lane + 64 * RFULL]);
    }
}

// ---------------------------------------------------------------------------
// Generic fallback (runtime shape) — proven-correct fused kernel from R2-R10.
// ---------------------------------------------------------------------------
__global__ __launch_bounds__(1024)
void fused_select_kernel(const float* __restrict__ x,
                         const float* __restrict__ pre_w,
                         const float* __restrict__ pre_b,
                         const float* __restrict__ W,
                         const float* __restrict__ bias,
                         float* __restrict__ out,
                         int T, int D, int K) {
    __shared__ double   s_sh[1024];
    __shared__ double   lg[1024];
    __shared__ unsigned flags[32];
    __shared__ int      sel[576];

    const int f    = blockIdx.x;
    const int tid  = threadIdx.x;
    const int wave = tid >> 6;
    const int lane = tid & 63;
    const int nw   = blockDim.x >> 6;
    const int n4   = D >> 2;

    const f4* wv = (const f4*)pre_w;
    for (int t = wave; t < T; t += nw) {
        const f4* xr = (const f4*)(x + ((size_t)f * T + t) * D);
        double acc = 0.0;
        for (int p = lane; p < n4; p += 64) acc += dot4d(xr[p], wv[p]);
#pragma unroll
        for (int off = 32; off > 0; off >>= 1) acc += __shfl_down(acc, off);
        if (lane == 0) s_sh[t] = acc + (double)pre_b[0];
    }
    if (tid < 32) flags[tid] = 0u;
    __syncthreads();

    if (tid < T) {
        const float* Wc = W + tid;
        double a0 = 0, a1 = 0, a2 = 0, a3 = 0;
        int tp = 0;
        for (; tp + 4 <= T; tp += 4) {
            a0 += s_sh[tp + 0] * (double)Wc[(size_t)(tp + 0) * T];
            a1 += s_sh[tp + 1] * (double)Wc[(size_t)(tp + 1) * T];
            a2 += s_sh[tp + 2] * (double)Wc[(size_t)(tp + 2) * T];
            a3 += s_sh[tp + 3] * (double)Wc[(size_t)(tp + 3) * T];
        }
        for (; tp < T; ++tp) a0 += s_sh[tp] * (double)Wc[(size_t)tp * T];
        lg[tid] = ((a0 + a1) + (a2 + a3)) + (double)bias[tid];
    }
    __syncthreads();
    if (tid < T) {
        const double v = lg[tid];
        int rank = 0;
        for (int tp = 0; tp < T; ++tp) {
            double u = lg[tp];
            rank += (u > v) || (u == v && tp < tid);
        }
        if (rank < K) atomicOr(&flags[tid >> 5], 1u << (tid & 31));
    }
    __syncthreads();
    if (tid < T) {
        if ((flags[tid >> 5] >> (tid & 31)) & 1u) {
            int pos = __popc(flags[tid >> 5] & ((1u << (tid & 31)) - 1u));
            for (int u2 = 0; u2 < (tid >> 5); ++u2) pos += __popc(flags[u2]);
            sel[pos] = tid;
        }
    }
    __syncthreads();
    for (int k2 = wave; k2 < K; k2 += nw) {
        int t = sel[k2];
        const f4* src = (const f4*)(x + ((size_t)f * T + t) * D);
        f4*       dst = (f4*)(out + ((size_t)f * K + k2) * D);
        for (int p = lane; p < n4; p += 64)
            __builtin_nontemporal_store(src[p], &dst[p]);
    }
}

// ---------------------------------------------------------------------------
extern "C" void kernel_launch(void* const* d_in, const int* in_sizes, int n_in,
                              void* d_out, int out_size, void* d_ws, size_t ws_size,
                              hipStream_t stream) {
    const float* x     = (const float*)d_in[0];
    const float* pre_w = (const float*)d_in[1];
    const float* pre_b = (const float*)d_in[2];
    const float* W     = (const float*)d_in[3];
    const float* bias  = (const float*)d_in[4];
    float* outp = (float*)d_out;

    const int D = in_sizes[1];          // pre_w is [1, D]
    const int T = in_sizes[4];          // trans_bias is [T]
    const int F = in_sizes[0] / (T * D);
    const int K = out_size / (F * D);

    if (T == 576 && D == 1408 && K == 144 && (F * T) % 64 == 0 && (F * K) % 4 == 0) {
        double* s_buf = (double*)d_ws;
        int*    idx   = (int*)((char*)d_ws + (size_t)F * T * sizeof(double));

        // Diagnostic: each phase repeated to exceed the ~507 µs harness fills
        // so its counters appear in rocprof top-5.
        score_k_rep<576, 1408, 4><<<(F * T) / 64, 256, 0, stream>>>(
            x, pre_w, pre_b, s_buf, 0);
        select_k_rep<576, 144, 48><<<F, 576, 0, stream>>>(s_buf, W, bias, idx, 0);
        gather_k_rep<576, 1408, 144, 9><<<(F * K) / 4, 256, 0, stream>>>(
            x, idx, outp, F, 0);
    } else {
        fused_select_kernel<<<F, 1024, 0, stream>>>(x, pre_w, pre_b, W, bias,
                                                    outp, T, D, K);
    }
}

// Round 12
// 246.199 us; speedup vs baseline: 10.1350x; 10.1350x over previous
//
#include <hip/hip_runtime.h>
#include <stdint.h>

typedef float f4 __attribute__((ext_vector_type(4)));

__device__ __forceinline__ double dot4d(f4 a, f4 b) {
    return (double)a.x * (double)b.x + (double)a.y * (double)b.y
         + (double)a.z * (double)b.z + (double)a.w * (double)b.w;
}

// ---------------------------------------------------------------------------
// One block per frame, 1024 threads (16 waves). Compile-time shape.
// v6 = R8 (253.7 µs, proven) with ONLY the select phase rebuilt per R11's
// diagnostic (select was 38.5 µs: f64-latency-bound, 45% VALUBusy, L2-resident
// W starved at 16-deep ILP):
//   Phase 2: GEMV in f32, 32 independent accumulators (L2-BW-bound ~11 µs).
//            Reference logits are f32; f64 path matched it for 11 rounds ->
//            gaps >> 1e-7 reorder noise. Tie semantics unchanged.
//   Phase 2b: rank-select on f32 (1-cyc compares), same stable
//            (value desc, index asc) == stable top-K of argsort(-softmax).
// Phases 1 (score, HBM roofline) and 4 (gather, roofline) byte-identical R8.
// ---------------------------------------------------------------------------
template <int T, int D, int K>
__global__ __launch_bounds__(1024)
void fused_v6_kernel(const float* __restrict__ x,
                     const float* __restrict__ pre_w,
                     const float* __restrict__ pre_b,
                     const float* __restrict__ W,
                     const float* __restrict__ bias,
                     float* __restrict__ out) {
    constexpr int N4   = D / 4;          // 352 f4 per row
    constexpr int NGRP = 64;             // 16-lane groups per block
    constexpr int RPG  = T / NGRP;       // 9 rows per group (exact)
    constexpr int NW   = (T + 31) / 32;
    constexpr int RFULL = N4 / 64;           // 5 full 64-lane passes (gather)
    constexpr int RREM  = N4 - RFULL * 64;   // 32 remaining f4 (gather)
    static_assert(N4 == 16 * 22 && RPG * NGRP == T && T % 32 == 0, "shape");

    __shared__ f4       w_sh[N4];
    __shared__ float    s32_sh[T];
    __shared__ float    lg32[T];
    __shared__ unsigned flags[NW];
    __shared__ int      sel[K];

    const int f    = blockIdx.x;
    const int tid  = threadIdx.x;
    const int sub  = tid & 15;           // lane within 16-lane group
    const int gid  = tid >> 4;           // group id 0..63
    const int wave = tid >> 6;           // wave id 0..15
    const int lane = tid & 63;

    for (int i = tid; i < N4; i += 1024) w_sh[i] = ((const f4*)pre_w)[i];
    if (tid < NW) flags[tid] = 0u;
    __syncthreads();

    // ---------------- Phase 1: per-token scores (R8-identical math) ----------------
    const double pb = (double)pre_b[0];
    for (int m = 0; m < RPG; ++m) {
        const int r = gid + NGRP * m;
        const f4* xr = (const f4*)(x + ((size_t)f * T + r) * D);
        double a0 = 0, a1 = 0, a2 = 0, a3 = 0;
        #pragma unroll 2
        for (int j = 0; j < 16; j += 4) {
            f4 v0 = xr[sub + 16 * (j + 0)];
            f4 v1 = xr[sub + 16 * (j + 1)];
            f4 v2 = xr[sub + 16 * (j + 2)];
            f4 v3 = xr[sub + 16 * (j + 3)];
            a0 += dot4d(v0, w_sh[sub + 16 * (j + 0)]);
            a1 += dot4d(v1, w_sh[sub + 16 * (j + 1)]);
            a2 += dot4d(v2, w_sh[sub + 16 * (j + 2)]);
            a3 += dot4d(v3, w_sh[sub + 16 * (j + 3)]);
        }
        {   // tail: j = 16..21 (6 f4)
            f4 v0 = xr[sub + 16 * 16];
            f4 v1 = xr[sub + 16 * 17];
            f4 v2 = xr[sub + 16 * 18];
            f4 v3 = xr[sub + 16 * 19];
            f4 v4 = xr[sub + 16 * 20];
            f4 v5 = xr[sub + 16 * 21];
            a0 += dot4d(v0, w_sh[sub + 16 * 16]);
            a1 += dot4d(v1, w_sh[sub + 16 * 17]);
            a2 += dot4d(v2, w_sh[sub + 16 * 18]);
            a3 += dot4d(v3, w_sh[sub + 16 * 19]);
            a0 += dot4d(v4, w_sh[sub + 16 * 20]);
            a1 += dot4d(v5, w_sh[sub + 16 * 21]);
        }
        double s = (a0 + a1) + (a2 + a3);
        s += __shfl_down(s, 8, 16);
        s += __shfl_down(s, 4, 16);
        s += __shfl_down(s, 2, 16);
        s += __shfl_down(s, 1, 16);
        if (sub == 0) s32_sh[r] = (float)(s + pb);
    }
    __syncthreads();

    // ---------------- Phase 2: f32 GEMV, 32 accumulators ----------------
    if (tid < T) {
        const float* Wc = W + tid;
        float acc[32];
        #pragma unroll
        for (int u = 0; u < 32; ++u) acc[u] = 0.0f;
        for (int tp = 0; tp < T; tp += 32) {
            #pragma unroll
            for (int u = 0; u < 32; ++u)
                acc[u] += s32_sh[tp + u] * Wc[(size_t)(tp + u) * T];
        }
        // in-place pairwise tree reduction (balanced)
        #pragma unroll
        for (int st = 16; st >= 1; st >>= 1) {
            #pragma unroll
            for (int u = 0; u < st; ++u) acc[u] = acc[2 * u] + acc[2 * u + 1];
        }
        lg32[tid] = acc[0] + bias[tid];
    }
    __syncthreads();

    // ---------------- Phase 2b: f32 rank-select ----------------
    if (tid < T) {
        const float v = lg32[tid];
        int rank = 0;
        #pragma unroll 8
        for (int tp = 0; tp < T; ++tp) {
            float u = lg32[tp];
            rank += (u > v) || (u == v && tp < tid);
        }
        if (rank < K) atomicOr(&flags[tid >> 5], 1u << (tid & 31));
    }
    __syncthreads();

    // ---------------- Phase 3: ascending compaction ----------------
    if (tid < T) {
        if ((flags[tid >> 5] >> (tid & 31)) & 1u) {
            int pos = __popc(flags[tid >> 5] & ((1u << (tid & 31)) - 1u));
            for (int u2 = 0; u2 < (tid >> 5); ++u2) pos += __popc(flags[u2]);
            sel[pos] = tid;
        }
    }
    __syncthreads();

    // ---------------- Phase 4: wave-per-row gather (R8-identical) ----------------
    for (int k2 = wave; k2 < K; k2 += 16) {
        const int t = sel[k2];
        const f4* src = (const f4*)(x + ((size_t)f * T + t) * D);
        f4*       dst = (f4*)(out + ((size_t)f * K + k2) * D);
        f4 v0 = src[lane + 64 * 0];
        f4 v1 = src[lane + 64 * 1];
        f4 v2 = src[lane + 64 * 2];
        f4 v3 = src[lane + 64 * 3];
        f4 v4 = src[lane + 64 * 4];
        __builtin_nontemporal_store(v0, &dst[lane + 64 * 0]);
        __builtin_nontemporal_store(v1, &dst[lane + 64 * 1]);
        __builtin_nontemporal_store(v2, &dst[lane + 64 * 2]);
        __builtin_nontemporal_store(v3, &dst[lane + 64 * 3]);
        __builtin_nontemporal_store(v4, &dst[lane + 64 * 4]);
        if (lane < RREM) {
            f4 v5 = src[lane + 64 * RFULL];
            __builtin_nontemporal_store(v5, &dst[lane + 64 * RFULL]);
        }
    }
}

// ---------------------------------------------------------------------------
// Generic fallback (runtime shape) — proven-correct fused kernel from R2-R11.
// ---------------------------------------------------------------------------
__global__ __launch_bounds__(1024)
void fused_select_kernel(const float* __restrict__ x,
                         const float* __restrict__ pre_w,
                         const float* __restrict__ pre_b,
                         const float* __restrict__ W,
                         const float* __restrict__ bias,
                         float* __restrict__ out,
                         int T, int D, int K) {
    __shared__ double   s_sh[1024];
    __shared__ double   lg[1024];
    __shared__ unsigned flags[32];
    __shared__ int      sel[576];

    const int f    = blockIdx.x;
    const int tid  = threadIdx.x;
    const int wave = tid >> 6;
    const int lane = tid & 63;
    const int nw   = blockDim.x >> 6;
    const int n4   = D >> 2;

    const f4* wv = (const f4*)pre_w;
    for (int t = wave; t < T; t += nw) {
        const f4* xr = (const f4*)(x + ((size_t)f * T + t) * D);
        double acc = 0.0;
        for (int p = lane; p < n4; p += 64) acc += dot4d(xr[p], wv[p]);
#pragma unroll
        for (int off = 32; off > 0; off >>= 1) acc += __shfl_down(acc, off);
        if (lane == 0) s_sh[t] = acc + (double)pre_b[0];
    }
    if (tid < 32) flags[tid] = 0u;
    __syncthreads();

    if (tid < T) {
        const float* Wc = W + tid;
        double a0 = 0, a1 = 0, a2 = 0, a3 = 0;
        int tp = 0;
        for (; tp + 4 <= T; tp += 4) {
            a0 += s_sh[tp + 0] * (double)Wc[(size_t)(tp + 0) * T];
            a1 += s_sh[tp + 1] * (double)Wc[(size_t)(tp + 1) * T];
            a2 += s_sh[tp + 2] * (double)Wc[(size_t)(tp + 2) * T];
            a3 += s_sh[tp + 3] * (double)Wc[(size_t)(tp + 3) * T];
        }
        for (; tp < T; ++tp) a0 += s_sh[tp] * (double)Wc[(size_t)tp * T];
        lg[tid] = ((a0 + a1) + (a2 + a3)) + (double)bias[tid];
    }
    __syncthreads();
    if (tid < T) {
        const double v = lg[tid];
        int rank = 0;
        for (int tp = 0; tp < T; ++tp) {
            double u = lg[tp];
            rank += (u > v) || (u == v && tp < tid);
        }
        if (rank < K) atomicOr(&flags[tid >> 5], 1u << (tid & 31));
    }
    __syncthreads();
    if (tid < T) {
        if ((flags[tid >> 5] >> (tid & 31)) & 1u) {
            int pos = __popc(flags[tid >> 5] & ((1u << (tid & 31)) - 1u));
            for (int u2 = 0; u2 < (tid >> 5); ++u2) pos += __popc(flags[u2]);
            sel[pos] = tid;
        }
    }
    __syncthreads();
    for (int k2 = wave; k2 < K; k2 += nw) {
        int t = sel[k2];
        const f4* src = (const f4*)(x + ((size_t)f * T + t) * D);
        f4*       dst = (f4*)(out + ((size_t)f * K + k2) * D);
        for (int p = lane; p < n4; p += 64)
            __builtin_nontemporal_store(src[p], &dst[p]);
    }
}

// ---------------------------------------------------------------------------
extern "C" void kernel_launch(void* const* d_in, const int* in_sizes, int n_in,
                              void* d_out, int out_size, void* d_ws, size_t ws_size,
                              hipStream_t stream) {
    const float* x     = (const float*)d_in[0];
    const float* pre_w = (const float*)d_in[1];
    const float* pre_b = (const float*)d_in[2];
    const float* W     = (const float*)d_in[3];
    const float* bias  = (const float*)d_in[4];
    float* outp = (float*)d_out;

    const int D = in_sizes[1];          // pre_w is [1, D]
    const int T = in_sizes[4];          // trans_bias is [T]
    const int F = in_sizes[0] / (T * D);
    const int K = out_size / (F * D);

    if (T == 576 && D == 1408 && K == 144) {
        fused_v6_kernel<576, 1408, 144><<<F, 1024, 0, stream>>>(
            x, pre_w, pre_b, W, bias, outp);
    } else {
        fused_select_kernel<<<F, 1024, 0, stream>>>(x, pre_w, pre_b, W, bias,
                                                    outp, T, D, K);
    }
}

// Round 13
// 241.075 us; speedup vs baseline: 10.3504x; 1.0213x over previous
//
#include <hip/hip_runtime.h>
#include <stdint.h>

typedef float f4 __attribute__((ext_vector_type(4)));

__device__ __forceinline__ double dot4d(f4 a, f4 b) {
    return (double)a.x * (double)b.x + (double)a.y * (double)b.y
         + (double)a.z * (double)b.z + (double)a.w * (double)b.w;
}

// ---------------------------------------------------------------------------
// One block per frame, 1024 threads (16 waves). Compile-time shape.
// v7 = R12 (246.2 µs, proven) with ONE change: gather does 2-row bursts
// (issue ~11 KB of loads before any store) to cut DRAM read<->write bus
// turnarounds in the mixed stream. Everything else byte-identical to R12.
// ---------------------------------------------------------------------------
template <int T, int D, int K>
__global__ __launch_bounds__(1024)
void fused_v7_kernel(const float* __restrict__ x,
                     const float* __restrict__ pre_w,
                     const float* __restrict__ pre_b,
                     const float* __restrict__ W,
                     const float* __restrict__ bias,
                     float* __restrict__ out) {
    constexpr int N4   = D / 4;          // 352 f4 per row
    constexpr int NGRP = 64;             // 16-lane groups per block
    constexpr int RPG  = T / NGRP;       // 9 rows per group (exact)
    constexpr int NW   = (T + 31) / 32;
    constexpr int RFULL = N4 / 64;           // 5 full 64-lane passes (gather)
    constexpr int RREM  = N4 - RFULL * 64;   // 32 remaining f4 (gather)
    constexpr int RPW  = K / 16;             // 9 gather rows per wave
    static_assert(N4 == 16 * 22 && RPG * NGRP == T && T % 32 == 0 &&
                  RPW * 16 == K, "shape");

    __shared__ f4       w_sh[N4];
    __shared__ float    s32_sh[T];
    __shared__ float    lg32[T];
    __shared__ unsigned flags[NW];
    __shared__ int      sel[K];

    const int f    = blockIdx.x;
    const int tid  = threadIdx.x;
    const int sub  = tid & 15;           // lane within 16-lane group
    const int gid  = tid >> 4;           // group id 0..63
    const int wave = tid >> 6;           // wave id 0..15
    const int lane = tid & 63;

    for (int i = tid; i < N4; i += 1024) w_sh[i] = ((const f4*)pre_w)[i];
    if (tid < NW) flags[tid] = 0u;
    __syncthreads();

    // ---------------- Phase 1: per-token scores (R8-identical math) ----------------
    const double pb = (double)pre_b[0];
    for (int m = 0; m < RPG; ++m) {
        const int r = gid + NGRP * m;
        const f4* xr = (const f4*)(x + ((size_t)f * T + r) * D);
        double a0 = 0, a1 = 0, a2 = 0, a3 = 0;
        #pragma unroll 2
        for (int j = 0; j < 16; j += 4) {
            f4 v0 = xr[sub + 16 * (j + 0)];
            f4 v1 = xr[sub + 16 * (j + 1)];
            f4 v2 = xr[sub + 16 * (j + 2)];
            f4 v3 = xr[sub + 16 * (j + 3)];
            a0 += dot4d(v0, w_sh[sub + 16 * (j + 0)]);
            a1 += dot4d(v1, w_sh[sub + 16 * (j + 1)]);
            a2 += dot4d(v2, w_sh[sub + 16 * (j + 2)]);
            a3 += dot4d(v3, w_sh[sub + 16 * (j + 3)]);
        }
        {   // tail: j = 16..21 (6 f4)
            f4 v0 = xr[sub + 16 * 16];
            f4 v1 = xr[sub + 16 * 17];
            f4 v2 = xr[sub + 16 * 18];
            f4 v3 = xr[sub + 16 * 19];
            f4 v4 = xr[sub + 16 * 20];
            f4 v5 = xr[sub + 16 * 21];
            a0 += dot4d(v0, w_sh[sub + 16 * 16]);
            a1 += dot4d(v1, w_sh[sub + 16 * 17]);
            a2 += dot4d(v2, w_sh[sub + 16 * 18]);
            a3 += dot4d(v3, w_sh[sub + 16 * 19]);
            a0 += dot4d(v4, w_sh[sub + 16 * 20]);
            a1 += dot4d(v5, w_sh[sub + 16 * 21]);
        }
        double s = (a0 + a1) + (a2 + a3);
        s += __shfl_down(s, 8, 16);
        s += __shfl_down(s, 4, 16);
        s += __shfl_down(s, 2, 16);
        s += __shfl_down(s, 1, 16);
        if (sub == 0) s32_sh[r] = (float)(s + pb);
    }
    __syncthreads();

    // ---------------- Phase 2: f32 GEMV, 32 accumulators (R12-identical) ----------------
    if (tid < T) {
        const float* Wc = W + tid;
        float acc[32];
        #pragma unroll
        for (int u = 0; u < 32; ++u) acc[u] = 0.0f;
        for (int tp = 0; tp < T; tp += 32) {
            #pragma unroll
            for (int u = 0; u < 32; ++u)
                acc[u] += s32_sh[tp + u] * Wc[(size_t)(tp + u) * T];
        }
        #pragma unroll
        for (int st = 16; st >= 1; st >>= 1) {
            #pragma unroll
            for (int u = 0; u < st; ++u) acc[u] = acc[2 * u] + acc[2 * u + 1];
        }
        lg32[tid] = acc[0] + bias[tid];
    }
    __syncthreads();

    // ---------------- Phase 2b: f32 rank-select (R12-identical) ----------------
    if (tid < T) {
        const float v = lg32[tid];
        int rank = 0;
        #pragma unroll 8
        for (int tp = 0; tp < T; ++tp) {
            float u = lg32[tp];
            rank += (u > v) || (u == v && tp < tid);
        }
        if (rank < K) atomicOr(&flags[tid >> 5], 1u << (tid & 31));
    }
    __syncthreads();

    // ---------------- Phase 3: ascending compaction (R12-identical) ----------------
    if (tid < T) {
        if ((flags[tid >> 5] >> (tid & 31)) & 1u) {
            int pos = __popc(flags[tid >> 5] & ((1u << (tid & 31)) - 1u));
            for (int u2 = 0; u2 < (tid >> 5); ++u2) pos += __popc(flags[u2]);
            sel[pos] = tid;
        }
    }
    __syncthreads();

    // ---------------- Phase 4: gather, 2-row bursts ----------------
    const f4* xf = (const f4*)(x + (size_t)f * T * D);
    f4*       of = (f4*)(out + (size_t)f * K * D);
    #pragma unroll 1
    for (int j = 0; j + 2 <= RPW; j += 2) {
        const int ka = wave + 16 * (j + 0);
        const int kb = wave + 16 * (j + 1);
        const f4* sa = xf + (size_t)sel[ka] * N4;
        const f4* sb = xf + (size_t)sel[kb] * N4;
        f4*       da = of + (size_t)ka * N4;
        f4*       db = of + (size_t)kb * N4;
        // all loads first (coarse read burst), then all stores
        f4 a0 = sa[lane + 64 * 0];
        f4 a1 = sa[lane + 64 * 1];
        f4 a2 = sa[lane + 64 * 2];
        f4 a3 = sa[lane + 64 * 3];
        f4 a4 = sa[lane + 64 * 4];
        f4 b0 = sb[lane + 64 * 0];
        f4 b1 = sb[lane + 64 * 1];
        f4 b2 = sb[lane + 64 * 2];
        f4 b3 = sb[lane + 64 * 3];
        f4 b4 = sb[lane + 64 * 4];
        f4 a5, b5;
        if (lane < RREM) {
            a5 = sa[lane + 64 * RFULL];
            b5 = sb[lane + 64 * RFULL];
        }
        __builtin_nontemporal_store(a0, &da[lane + 64 * 0]);
        __builtin_nontemporal_store(a1, &da[lane + 64 * 1]);
        __builtin_nontemporal_store(a2, &da[lane + 64 * 2]);
        __builtin_nontemporal_store(a3, &da[lane + 64 * 3]);
        __builtin_nontemporal_store(a4, &da[lane + 64 * 4]);
        __builtin_nontemporal_store(b0, &db[lane + 64 * 0]);
        __builtin_nontemporal_store(b1, &db[lane + 64 * 1]);
        __builtin_nontemporal_store(b2, &db[lane + 64 * 2]);
        __builtin_nontemporal_store(b3, &db[lane + 64 * 3]);
        __builtin_nontemporal_store(b4, &db[lane + 64 * 4]);
        if (lane < RREM) {
            __builtin_nontemporal_store(a5, &da[lane + 64 * RFULL]);
            __builtin_nontemporal_store(b5, &db[lane + 64 * RFULL]);
        }
    }
    if (RPW & 1) {   // last (odd) row
        const int k2 = wave + 16 * (RPW - 1);
        const f4* src = xf + (size_t)sel[k2] * N4;
        f4*       dst = of + (size_t)k2 * N4;
        f4 v0 = src[lane + 64 * 0];
        f4 v1 = src[lane + 64 * 1];
        f4 v2 = src[lane + 64 * 2];
        f4 v3 = src[lane + 64 * 3];
        f4 v4 = src[lane + 64 * 4];
        __builtin_nontemporal_store(v0, &dst[lane + 64 * 0]);
        __builtin_nontemporal_store(v1, &dst[lane + 64 * 1]);
        __builtin_nontemporal_store(v2, &dst[lane + 64 * 2]);
        __builtin_nontemporal_store(v3, &dst[lane + 64 * 3]);
        __builtin_nontemporal_store(v4, &dst[lane + 64 * 4]);
        if (lane < RREM) {
            f4 v5 = src[lane + 64 * RFULL];
            __builtin_nontemporal_store(v5, &dst[lane + 64 * RFULL]);
        }
    }
}

// ---------------------------------------------------------------------------
// Generic fallback (runtime shape) — proven-correct fused kernel from R2-R12.
// ---------------------------------------------------------------------------
__global__ __launch_bounds__(1024)
void fused_select_kernel(const float* __restrict__ x,
                         const float* __restrict__ pre_w,
                         const float* __restrict__ pre_b,
                         const float* __restrict__ W,
                         const float* __restrict__ bias,
                         float* __restrict__ out,
                         int T, int D, int K) {
    __shared__ double   s_sh[1024];
    __shared__ double   lg[1024];
    __shared__ unsigned flags[32];
    __shared__ int      sel[576];

    const int f    = blockIdx.x;
    const int tid  = threadIdx.x;
    const int wave = tid >> 6;
    const int lane = tid & 63;
    const int nw   = blockDim.x >> 6;
    const int n4   = D >> 2;

    const f4* wv = (const f4*)pre_w;
    for (int t = wave; t < T; t += nw) {
        const f4* xr = (const f4*)(x + ((size_t)f * T + t) * D);
        double acc = 0.0;
        for (int p = lane; p < n4; p += 64) acc += dot4d(xr[p], wv[p]);
#pragma unroll
        for (int off = 32; off > 0; off >>= 1) acc += __shfl_down(acc, off);
        if (lane == 0) s_sh[t] = acc + (double)pre_b[0];
    }
    if (tid < 32) flags[tid] = 0u;
    __syncthreads();

    if (tid < T) {
        const float* Wc = W + tid;
        double a0 = 0, a1 = 0, a2 = 0, a3 = 0;
        int tp = 0;
        for (; tp + 4 <= T; tp += 4) {
            a0 += s_sh[tp + 0] * (double)Wc[(size_t)(tp + 0) * T];
            a1 += s_sh[tp + 1] * (double)Wc[(size_t)(tp + 1) * T];
            a2 += s_sh[tp + 2] * (double)Wc[(size_t)(tp + 2) * T];
            a3 += s_sh[tp + 3] * (double)Wc[(size_t)(tp + 3) * T];
        }
        for (; tp < T; ++tp) a0 += s_sh[tp] * (double)Wc[(size_t)tp * T];
        lg[tid] = ((a0 + a1) + (a2 + a3)) + (double)bias[tid];
    }
    __syncthreads();
    if (tid < T) {
        const double v = lg[tid];
        int rank = 0;
        for (int tp = 0; tp < T; ++tp) {
            double u = lg[tp];
            rank += (u > v) || (u == v && tp < tid);
        }
        if (rank < K) atomicOr(&flags[tid >> 5], 1u << (tid & 31));
    }
    __syncthreads();
    if (tid < T) {
        if ((flags[tid >> 5] >> (tid & 31)) & 1u) {
            int pos = __popc(flags[tid >> 5] & ((1u << (tid & 31)) - 1u));
            for (int u2 = 0; u2 < (tid >> 5); ++u2) pos += __popc(flags[u2]);
            sel[pos] = tid;
        }
    }
    __syncthreads();
    for (int k2 = wave; k2 < K; k2 += nw) {
        int t = sel[k2];
        const f4* src = (const f4*)(x + ((size_t)f * T + t) * D);
        f4*       dst = (f4*)(out + ((size_t)f * K + k2) * D);
        for (int p = lane; p < n4; p += 64)
            __builtin_nontemporal_store(src[p], &dst[p]);
    }
}

// ---------------------------------------------------------------------------
extern "C" void kernel_launch(void* const* d_in, const int* in_sizes, int n_in,
                              void* d_out, int out_size, void* d_ws, size_t ws_size,
                              hipStream_t stream) {
    const float* x     = (const float*)d_in[0];
    const float* pre_w = (const float*)d_in[1];
    const float* pre_b = (const float*)d_in[2];
    const float* W     = (const float*)d_in[3];
    const float* bias  = (const float*)d_in[4];
    float* outp = (float*)d_out;

    const int D = in_sizes[1];          // pre_w is [1, D]
    const int T = in_sizes[4];          // trans_bias is [T]
    const int F = in_sizes[0] / (T * D);
    const int K = out_size / (F * D);

    if (T == 576 && D == 1408 && K == 144) {
        fused_v7_kernel<576, 1408, 144><<<F, 1024, 0, stream>>>(
            x, pre_w, pre_b, W, bias, outp);
    } else {
        fused_select_kernel<<<F, 1024, 0, stream>>>(x, pre_w, pre_b, W, bias,
                                                    outp, T, D, K);
    }
}

// Round 14
// 239.414 us; speedup vs baseline: 10.4222x; 1.0069x over previous
//
#include <hip/hip_runtime.h>
#include <stdint.h>

typedef float f4 __attribute__((ext_vector_type(4)));

__device__ __forceinline__ double dot4d(f4 a, f4 b) {
    return (double)a.x * (double)b.x + (double)a.y * (double)b.y
         + (double)a.z * (double)b.z + (double)a.w * (double)b.w;
}

// ---------------------------------------------------------------------------
// One block per frame, 1024 threads (16 waves). Compile-time shape.
// v8 = R13 (241.1 µs, proven) with ONE change: gather burst depth 2 -> 3 rows
// (9 rows/wave = 3x3 exactly; ~16 KB read burst before each store burst) to
// further coarsen DRAM read<->write alternation. ~72 live VGPRs in f4 regs —
// under the 128 cliff at 16 waves/CU. Everything else byte-identical to R13.
// ---------------------------------------------------------------------------
template <int T, int D, int K>
__global__ __launch_bounds__(1024)
void fused_v8_kernel(const float* __restrict__ x,
                     const float* __restrict__ pre_w,
                     const float* __restrict__ pre_b,
                     const float* __restrict__ W,
                     const float* __restrict__ bias,
                     float* __restrict__ out) {
    constexpr int N4   = D / 4;          // 352 f4 per row
    constexpr int NGRP = 64;             // 16-lane groups per block
    constexpr int RPG  = T / NGRP;       // 9 rows per group (exact)
    constexpr int NW   = (T + 31) / 32;
    constexpr int RFULL = N4 / 64;           // 5 full 64-lane passes (gather)
    constexpr int RREM  = N4 - RFULL * 64;   // 32 remaining f4 (gather)
    constexpr int RPW  = K / 16;             // 9 gather rows per wave
    static_assert(N4 == 16 * 22 && RPG * NGRP == T && T % 32 == 0 &&
                  RPW == 9, "shape");

    __shared__ f4       w_sh[N4];
    __shared__ float    s32_sh[T];
    __shared__ float    lg32[T];
    __shared__ unsigned flags[NW];
    __shared__ int      sel[K];

    const int f    = blockIdx.x;
    const int tid  = threadIdx.x;
    const int sub  = tid & 15;           // lane within 16-lane group
    const int gid  = tid >> 4;           // group id 0..63
    const int wave = tid >> 6;           // wave id 0..15
    const int lane = tid & 63;

    for (int i = tid; i < N4; i += 1024) w_sh[i] = ((const f4*)pre_w)[i];
    if (tid < NW) flags[tid] = 0u;
    __syncthreads();

    // ---------------- Phase 1: per-token scores (R8-identical math) ----------------
    const double pb = (double)pre_b[0];
    for (int m = 0; m < RPG; ++m) {
        const int r = gid + NGRP * m;
        const f4* xr = (const f4*)(x + ((size_t)f * T + r) * D);
        double a0 = 0, a1 = 0, a2 = 0, a3 = 0;
        #pragma unroll 2
        for (int j = 0; j < 16; j += 4) {
            f4 v0 = xr[sub + 16 * (j + 0)];
            f4 v1 = xr[sub + 16 * (j + 1)];
            f4 v2 = xr[sub + 16 * (j + 2)];
            f4 v3 = xr[sub + 16 * (j + 3)];
            a0 += dot4d(v0, w_sh[sub + 16 * (j + 0)]);
            a1 += dot4d(v1, w_sh[sub + 16 * (j + 1)]);
            a2 += dot4d(v2, w_sh[sub + 16 * (j + 2)]);
            a3 += dot4d(v3, w_sh[sub + 16 * (j + 3)]);
        }
        {   // tail: j = 16..21 (6 f4)
            f4 v0 = xr[sub + 16 * 16];
            f4 v1 = xr[sub + 16 * 17];
            f4 v2 = xr[sub + 16 * 18];
            f4 v3 = xr[sub + 16 * 19];
            f4 v4 = xr[sub + 16 * 20];
            f4 v5 = xr[sub + 16 * 21];
            a0 += dot4d(v0, w_sh[sub + 16 * 16]);
            a1 += dot4d(v1, w_sh[sub + 16 * 17]);
            a2 += dot4d(v2, w_sh[sub + 16 * 18]);
            a3 += dot4d(v3, w_sh[sub + 16 * 19]);
            a0 += dot4d(v4, w_sh[sub + 16 * 20]);
            a1 += dot4d(v5, w_sh[sub + 16 * 21]);
        }
        double s = (a0 + a1) + (a2 + a3);
        s += __shfl_down(s, 8, 16);
        s += __shfl_down(s, 4, 16);
        s += __shfl_down(s, 2, 16);
        s += __shfl_down(s, 1, 16);
        if (sub == 0) s32_sh[r] = (float)(s + pb);
    }
    __syncthreads();

    // ---------------- Phase 2: f32 GEMV, 32 accumulators (R12-identical) ----------------
    if (tid < T) {
        const float* Wc = W + tid;
        float acc[32];
        #pragma unroll
        for (int u = 0; u < 32; ++u) acc[u] = 0.0f;
        for (int tp = 0; tp < T; tp += 32) {
            #pragma unroll
            for (int u = 0; u < 32; ++u)
                acc[u] += s32_sh[tp + u] * Wc[(size_t)(tp + u) * T];
        }
        #pragma unroll
        for (int st = 16; st >= 1; st >>= 1) {
            #pragma unroll
            for (int u = 0; u < st; ++u) acc[u] = acc[2 * u] + acc[2 * u + 1];
        }
        lg32[tid] = acc[0] + bias[tid];
    }
    __syncthreads();

    // ---------------- Phase 2b: f32 rank-select (R12-identical) ----------------
    if (tid < T) {
        const float v = lg32[tid];
        int rank = 0;
        #pragma unroll 8
        for (int tp = 0; tp < T; ++tp) {
            float u = lg32[tp];
            rank += (u > v) || (u == v && tp < tid);
        }
        if (rank < K) atomicOr(&flags[tid >> 5], 1u << (tid & 31));
    }
    __syncthreads();

    // ---------------- Phase 3: ascending compaction (R12-identical) ----------------
    if (tid < T) {
        if ((flags[tid >> 5] >> (tid & 31)) & 1u) {
            int pos = __popc(flags[tid >> 5] & ((1u << (tid & 31)) - 1u));
            for (int u2 = 0; u2 < (tid >> 5); ++u2) pos += __popc(flags[u2]);
            sel[pos] = tid;
        }
    }
    __syncthreads();

    // ---------------- Phase 4: gather, 3-row bursts (9 = 3x3 exact) ----------------
    const f4* xf = (const f4*)(x + (size_t)f * T * D);
    f4*       of = (f4*)(out + (size_t)f * K * D);
    #pragma unroll 1
    for (int j = 0; j < RPW; j += 3) {
        const int ka = wave + 16 * (j + 0);
        const int kb = wave + 16 * (j + 1);
        const int kc = wave + 16 * (j + 2);
        const f4* sa = xf + (size_t)sel[ka] * N4;
        const f4* sb = xf + (size_t)sel[kb] * N4;
        const f4* sc = xf + (size_t)sel[kc] * N4;
        f4*       da = of + (size_t)ka * N4;
        f4*       db = of + (size_t)kb * N4;
        f4*       dc = of + (size_t)kc * N4;
        // all loads first (coarse read burst), then all stores
        f4 a0 = sa[lane + 64 * 0];
        f4 a1 = sa[lane + 64 * 1];
        f4 a2 = sa[lane + 64 * 2];
        f4 a3 = sa[lane + 64 * 3];
        f4 a4 = sa[lane + 64 * 4];
        f4 b0 = sb[lane + 64 * 0];
        f4 b1 = sb[lane + 64 * 1];
        f4 b2 = sb[lane + 64 * 2];
        f4 b3 = sb[lane + 64 * 3];
        f4 b4 = sb[lane + 64 * 4];
        f4 c0 = sc[lane + 64 * 0];
        f4 c1 = sc[lane + 64 * 1];
        f4 c2 = sc[lane + 64 * 2];
        f4 c3 = sc[lane + 64 * 3];
        f4 c4 = sc[lane + 64 * 4];
        f4 a5, b5, c5;
        if (lane < RREM) {
            a5 = sa[lane + 64 * RFULL];
            b5 = sb[lane + 64 * RFULL];
            c5 = sc[lane + 64 * RFULL];
        }
        __builtin_nontemporal_store(a0, &da[lane + 64 * 0]);
        __builtin_nontemporal_store(a1, &da[lane + 64 * 1]);
        __builtin_nontemporal_store(a2, &da[lane + 64 * 2]);
        __builtin_nontemporal_store(a3, &da[lane + 64 * 3]);
        __builtin_nontemporal_store(a4, &da[lane + 64 * 4]);
        __builtin_nontemporal_store(b0, &db[lane + 64 * 0]);
        __builtin_nontemporal_store(b1, &db[lane + 64 * 1]);
        __builtin_nontemporal_store(b2, &db[lane + 64 * 2]);
        __builtin_nontemporal_store(b3, &db[lane + 64 * 3]);
        __builtin_nontemporal_store(b4, &db[lane + 64 * 4]);
        __builtin_nontemporal_store(c0, &dc[lane + 64 * 0]);
        __builtin_nontemporal_store(c1, &dc[lane + 64 * 1]);
        __builtin_nontemporal_store(c2, &dc[lane + 64 * 2]);
        __builtin_nontemporal_store(c3, &dc[lane + 64 * 3]);
        __builtin_nontemporal_store(c4, &dc[lane + 64 * 4]);
        if (lane < RREM) {
            __builtin_nontemporal_store(a5, &da[lane + 64 * RFULL]);
            __builtin_nontemporal_store(b5, &db[lane + 64 * RFULL]);
            __builtin_nontemporal_store(c5, &dc[lane + 64 * RFULL]);
        }
    }
}

// ---------------------------------------------------------------------------
// Generic fallback (runtime shape) — proven-correct fused kernel from R2-R13.
// ---------------------------------------------------------------------------
__global__ __launch_bounds__(1024)
void fused_select_kernel(const float* __restrict__ x,
                         const float* __restrict__ pre_w,
                         const float* __restrict__ pre_b,
                         const float* __restrict__ W,
                         const float* __restrict__ bias,
                         float* __restrict__ out,
                         int T, int D, int K) {
    __shared__ double   s_sh[1024];
    __shared__ double   lg[1024];
    __shared__ unsigned flags[32];
    __shared__ int      sel[576];

    const int f    = blockIdx.x;
    const int tid  = threadIdx.x;
    const int wave = tid >> 6;
    const int lane = tid & 63;
    const int nw   = blockDim.x >> 6;
    const int n4   = D >> 2;

    const f4* wv = (const f4*)pre_w;
    for (int t = wave; t < T; t += nw) {
        const f4* xr = (const f4*)(x + ((size_t)f * T + t) * D);
        double acc = 0.0;
        for (int p = lane; p < n4; p += 64) acc += dot4d(xr[p], wv[p]);
#pragma unroll
        for (int off = 32; off > 0; off >>= 1) acc += __shfl_down(acc, off);
        if (lane == 0) s_sh[t] = acc + (double)pre_b[0];
    }
    if (tid < 32) flags[tid] = 0u;
    __syncthreads();

    if (tid < T) {
        const float* Wc = W + tid;
        double a0 = 0, a1 = 0, a2 = 0, a3 = 0;
        int tp = 0;
        for (; tp + 4 <= T; tp += 4) {
            a0 += s_sh[tp + 0] * (double)Wc[(size_t)(tp + 0) * T];
            a1 += s_sh[tp + 1] * (double)Wc[(size_t)(tp + 1) * T];
            a2 += s_sh[tp + 2] * (double)Wc[(size_t)(tp + 2) * T];
            a3 += s_sh[tp + 3] * (double)Wc[(size_t)(tp + 3) * T];
        }
        for (; tp < T; ++tp) a0 += s_sh[tp] * (double)Wc[(size_t)tp * T];
        lg[tid] = ((a0 + a1) + (a2 + a3)) + (double)bias[tid];
    }
    __syncthreads();
    if (tid < T) {
        const double v = lg[tid];
        int rank = 0;
        for (int tp = 0; tp < T; ++tp) {
            double u = lg[tp];
            rank += (u > v) || (u == v && tp < tid);
        }
        if (rank < K) atomicOr(&flags[tid >> 5], 1u << (tid & 31));
    }
    __syncthreads();
    if (tid < T) {
        if ((flags[tid >> 5] >> (tid & 31)) & 1u) {
            int pos = __popc(flags[tid >> 5] & ((1u << (tid & 31)) - 1u));
            for (int u2 = 0; u2 < (tid >> 5); ++u2) pos += __popc(flags[u2]);
            sel[pos] = tid;
        }
    }
    __syncthreads();
    for (int k2 = wave; k2 < K; k2 += nw) {
        int t = sel[k2];
        const f4* src = (const f4*)(x + ((size_t)f * T + t) * D);
        f4*       dst = (f4*)(out + ((size_t)f * K + k2) * D);
        for (int p = lane; p < n4; p += 64)
            __builtin_nontemporal_store(src[p], &dst[p]);
    }
}

// ---------------------------------------------------------------------------
extern "C" void kernel_launch(void* const* d_in, const int* in_sizes, int n_in,
                              void* d_out, int out_size, void* d_ws, size_t ws_size,
                              hipStream_t stream) {
    const float* x     = (const float*)d_in[0];
    const float* pre_w = (const float*)d_in[1];
    const float* pre_b = (const float*)d_in[2];
    const float* W     = (const float*)d_in[3];
    const float* bias  = (const float*)d_in[4];
    float* outp = (float*)d_out;

    const int D = in_sizes[1];          // pre_w is [1, D]
    const int T = in_sizes[4];          // trans_bias is [T]
    const int F = in_sizes[0] / (T * D);
    const int K = out_size / (F * D);

    if (T == 576 && D == 1408 && K == 144) {
        fused_v8_kernel<576, 1408, 144><<<F, 1024, 0, stream>>>(
            x, pre_w, pre_b, W, bias, outp);
    } else {
        fused_select_kernel<<<F, 1024, 0, stream>>>(x, pre_w, pre_b, W, bias,
                                                    outp, T, D, K);
    }
}